// Round 1
// baseline (1458.249 us; speedup 1.0000x reference)
//
#include <hip/hip_runtime.h>

using u16 = unsigned short;
typedef __bf16 bf16x8 __attribute__((ext_vector_type(8)));
typedef float  f32x4  __attribute__((ext_vector_type(4)));
typedef short  s16x4  __attribute__((ext_vector_type(4)));

#define LOG2E 1.44269504088896340736f

__device__ __forceinline__ u16 f2bf(float f) {
  union { float f; unsigned u; } a; a.f = f;
  unsigned r = (a.u + 0x7FFFu + ((a.u >> 16) & 1u)) >> 16;
  return (u16)r;
}

// async global->LDS, 16B per lane; LDS dest = wave-uniform base + lane*16
__device__ __forceinline__ void gl_lds16(const void* g, void* l) {
  __builtin_amdgcn_global_load_lds((const __attribute__((address_space(1))) void*)g,
                                   (__attribute__((address_space(3))) void*)l, 16, 0, 0);
}

// ---------------------------------------------------------------------------
// prep: transpose 5 weight matrices [768,768] f32 -> bf16 Wt[j][d] (= W^T)
// grid (12,12,5), block 256
__global__ __launch_bounds__(256) void prep_w(const float* __restrict__ w0, const float* __restrict__ w1,
                                              const float* __restrict__ w2, const float* __restrict__ w3,
                                              const float* __restrict__ w4, u16* __restrict__ Wt) {
  int x = blockIdx.x, y = blockIdx.y, z = blockIdx.z;
  const float* srcs[5] = {w0, w1, w2, w3, w4};
  const float* s = srcs[z] + (size_t)(y * 64) * 768 + x * 64;       // rows d, cols j
  u16* d = Wt + (size_t)z * 589824 + (size_t)(x * 64) * 768 + y * 64; // rows j, cols d
  __shared__ float t[64 * 68];
  int tid = threadIdx.x;
#pragma unroll
  for (int r = 0; r < 4; ++r) {
    int row = r * 16 + (tid >> 4), ch = tid & 15;
    *(f32x4*)(t + row * 68 + ch * 4) = *(const f32x4*)(s + (size_t)row * 768 + ch * 4);
  }
  __syncthreads();
#pragma unroll
  for (int r = 0; r < 4; ++r) {
    int orow = r * 16 + (tid >> 4), ch = tid & 15;
    ushort4 o;
    o.x = f2bf(t[(ch * 4 + 0) * 68 + orow]);
    o.y = f2bf(t[(ch * 4 + 1) * 68 + orow]);
    o.z = f2bf(t[(ch * 4 + 2) * 68 + orow]);
    o.w = f2bf(t[(ch * 4 + 3) * 68 + orow]);
    *(ushort4*)(d + (size_t)orow * 768 + ch * 4) = o;
  }
}

__global__ __launch_bounds__(256) void copy_biases(const float* __restrict__ b0, const float* __restrict__ b1,
                                                   const float* __restrict__ b2, const float* __restrict__ b3,
                                                   float* __restrict__ dst) {
  int i = blockIdx.x * 256 + threadIdx.x;
  if (i < 768) { dst[i] = b0[i]; dst[768 + i] = b1[i]; dst[1536 + i] = b2[i]; dst[2304 + i] = b3[i]; }
}

// features f32 -> bf16, exact grid 12288*256*4 = 12582912 elems
__global__ __launch_bounds__(256) void convert_x(const float* __restrict__ X, u16* __restrict__ Y) {
  size_t i = (size_t)blockIdx.x * 256 + threadIdx.x;
  f32x4 v = *(const f32x4*)(X + i * 4);
  ushort4 o; o.x = f2bf(v[0]); o.y = f2bf(v[1]); o.z = f2bf(v[2]); o.w = f2bf(v[3]);
  *(ushort4*)(Y + i * 4) = o;
}

// LN(loc + pos) -> bf16, one wave per row; grid 4096, block 256
__global__ __launch_bounds__(256) void ln_rows(const float* __restrict__ L, const float* __restrict__ P,
                                               const float* __restrict__ gamma, const float* __restrict__ beta,
                                               u16* __restrict__ out) {
  int wave = threadIdx.x >> 6, lane = threadIdx.x & 63;
  int row = blockIdx.x * 4 + wave;
  int n = row & 1023;
  const f32x4* lp = (const f32x4*)(L + (size_t)row * 768);
  const f32x4* pp = (const f32x4*)(P + (size_t)n * 768);
  f32x4 x[3];
  float s = 0.f, ss = 0.f;
#pragma unroll
  for (int k = 0; k < 3; ++k) {
    f32x4 v = lp[lane + k * 64] + pp[lane + k * 64];
    x[k] = v;
    s += v[0] + v[1] + v[2] + v[3];
    ss += v[0] * v[0] + v[1] * v[1] + v[2] * v[2] + v[3] * v[3];
  }
#pragma unroll
  for (int off = 1; off < 64; off <<= 1) { s += __shfl_xor(s, off); ss += __shfl_xor(ss, off); }
  float mean = s * (1.0f / 768.0f);
  float var = ss * (1.0f / 768.0f) - mean * mean;
  float rstd = rsqrtf(var + 1e-5f);
#pragma unroll
  for (int k = 0; k < 3; ++k) {
    f32x4 g = *(const f32x4*)(gamma + (lane + k * 64) * 4);
    f32x4 bb = *(const f32x4*)(beta + (lane + k * 64) * 4);
    ushort4 o;
    o.x = f2bf((x[k][0] - mean) * rstd * g[0] + bb[0]);
    o.y = f2bf((x[k][1] - mean) * rstd * g[1] + bb[1]);
    o.z = f2bf((x[k][2] - mean) * rstd * g[2] + bb[2]);
    o.w = f2bf((x[k][3] - mean) * rstd * g[3] + bb[3]);
    *(ushort4*)(out + (size_t)row * 768 + (lane + k * 64) * 4) = o;
  }
}

// 64x64 bf16 tile transpose. grid (16, 12, 16).
// mode 0: normed [b,n,d] -> normt [b,d,n]   (y = d-tile)
// mode 1: Vb [b*n, h*64+d] -> Vt [(b,h), d, n]  (y = h)
__global__ __launch_bounds__(256) void transpose_bf16(const u16* __restrict__ src, u16* __restrict__ dst, int mode) {
  int x = blockIdx.x, y = blockIdx.y, z = blockIdx.z;
  const u16* s = src + ((size_t)(z * 1024 + x * 64)) * 768 + y * 64;
  u16* d = (mode == 0) ? dst + ((size_t)(z * 768 + y * 64)) * 1024 + x * 64
                       : dst + ((size_t)(z * 12 + y)) * 64 * 1024 + x * 64;
  __shared__ u16 t[64 * 72];
  int tid = threadIdx.x;
#pragma unroll
  for (int r = 0; r < 2; ++r) {
    int row = r * 32 + (tid >> 3), ch = tid & 7;
    *(uint4*)(t + row * 72 + ch * 8) = *(const uint4*)(s + (size_t)row * 768 + ch * 8);
  }
  __syncthreads();
#pragma unroll
  for (int r = 0; r < 2; ++r) {
    int orow = r * 32 + (tid >> 3), ch = tid & 7;
    union { u16 a[8]; uint4 v; } tmp;
#pragma unroll
    for (int j = 0; j < 8; ++j) tmp.a[j] = t[(ch * 8 + j) * 72 + orow];
    *(uint4*)(d + (size_t)orow * 1024 + ch * 8) = tmp.v;
  }
}

// ---------------------------------------------------------------------------
// m97-style NT GEMM: C[m,n] = scale * sum_k A[m,k]*B[n,k] (+ bias[n])
// A,B bf16 k-major. 128x128 tile, BK=32, global_load_lds + XOR chunk swizzle.
// grid (N/128, M/128, batch), block 256.
__global__ __launch_bounds__(256) void gemm_bt(
    const u16* __restrict__ A, int lda, long As_,
    const u16* __restrict__ B, int ldb, long Bs_,
    void* __restrict__ C, int ldc, long Cs_, int c_bf16,
    const float* __restrict__ bias, int biasStride,
    int K, float scale) {
  int nt = blockIdx.x, mt = blockIdx.y, z = blockIdx.z;
  A += (size_t)z * As_;
  B += (size_t)z * Bs_;
  __shared__ u16 Als[128 * 32];
  __shared__ u16 Bls[128 * 32];
  int tid = threadIdx.x, wave = tid >> 6, lane = tid & 63;
  int quad = lane >> 4, l15 = lane & 15;
  int wr = wave >> 1, wc = wave & 1;

  // staging: each wave does 2 calls of 1KB each for A and for B (16 rows x 64B)
  int rA0 = (wave * 2 + 0) * 16 + (lane >> 2);
  int rA1 = (wave * 2 + 1) * 16 + (lane >> 2);
  int cg = (lane & 3) ^ ((lane >> 3) & 3);  // global 16B-chunk, XOR-swizzled position
  const u16* ga0 = A + (size_t)(mt * 128 + rA0) * lda + cg * 8;
  const u16* ga1 = A + (size_t)(mt * 128 + rA1) * lda + cg * 8;
  const u16* gb0 = B + (size_t)(nt * 128 + rA0) * ldb + cg * 8;
  const u16* gb1 = B + (size_t)(nt * 128 + rA1) * ldb + cg * 8;
  u16* la0 = Als + (wave * 2 + 0) * 512;
  u16* la1 = Als + (wave * 2 + 1) * 512;
  u16* lb0 = Bls + (wave * 2 + 0) * 512;
  u16* lb1 = Bls + (wave * 2 + 1) * 512;

  f32x4 acc[4][4] = {};

  int aoff[4], boff[4];
#pragma unroll
  for (int t = 0; t < 4; ++t) {
    int ra = wr * 64 + t * 16 + l15;
    aoff[t] = ra * 32 + ((quad ^ ((ra >> 1) & 3)) * 8);
    int rb = wc * 64 + t * 16 + l15;
    boff[t] = rb * 32 + ((quad ^ ((rb >> 1) & 3)) * 8);
  }

  for (int kt = 0; kt < K; kt += 32) {
    __syncthreads();
    gl_lds16(ga0 + kt, la0);
    gl_lds16(ga1 + kt, la1);
    gl_lds16(gb0 + kt, lb0);
    gl_lds16(gb1 + kt, lb1);
    __syncthreads();
    bf16x8 af[4], bf[4];
#pragma unroll
    for (int i = 0; i < 4; ++i) af[i] = *(const bf16x8*)(Als + aoff[i]);
#pragma unroll
    for (int j = 0; j < 4; ++j) bf[j] = *(const bf16x8*)(Bls + boff[j]);
#pragma unroll
    for (int i = 0; i < 4; ++i)
#pragma unroll
      for (int j = 0; j < 4; ++j)
        acc[i][j] = __builtin_amdgcn_mfma_f32_16x16x32_bf16(af[i], bf[j], acc[i][j], 0, 0, 0);
  }

  float bv[4] = {0.f, 0.f, 0.f, 0.f};
  if (bias) {
#pragma unroll
    for (int j = 0; j < 4; ++j)
      bv[j] = bias[(size_t)z * biasStride + nt * 128 + wc * 64 + j * 16 + l15];
  }
  if (c_bf16) {
    u16* Cb = (u16*)C + (size_t)z * Cs_;
#pragma unroll
    for (int i = 0; i < 4; ++i)
#pragma unroll
      for (int j = 0; j < 4; ++j)
#pragma unroll
        for (int r = 0; r < 4; ++r) {
          int row = mt * 128 + wr * 64 + i * 16 + quad * 4 + r;
          int col = nt * 128 + wc * 64 + j * 16 + l15;
          Cb[(size_t)row * ldc + col] = f2bf(acc[i][j][r] * scale + bv[j]);
        }
  } else {
    float* Cf = (float*)C + (size_t)z * Cs_;
#pragma unroll
    for (int i = 0; i < 4; ++i)
#pragma unroll
      for (int j = 0; j < 4; ++j)
#pragma unroll
        for (int r = 0; r < 4; ++r) {
          int row = mt * 128 + wr * 64 + i * 16 + quad * 4 + r;
          int col = nt * 128 + wc * 64 + j * 16 + l15;
          Cf[(size_t)row * ldc + col] = acc[i][j][r] * scale + bv[j];
        }
  }
}

// row softmax: G f32 [row,1024] -> P bf16. grid 16384, block 256.
__global__ __launch_bounds__(256) void softmax_rows(const float* __restrict__ G, u16* __restrict__ P) {
  int row = blockIdx.x, tid = threadIdx.x, wave = tid >> 6, lane = tid & 63;
  f32x4 v = *(const f32x4*)(G + (size_t)row * 1024 + tid * 4);
  float mx = fmaxf(fmaxf(v[0], v[1]), fmaxf(v[2], v[3]));
#pragma unroll
  for (int off = 1; off < 64; off <<= 1) mx = fmaxf(mx, __shfl_xor(mx, off));
  __shared__ float red[8];
  if (lane == 0) red[wave] = mx;
  __syncthreads();
  mx = fmaxf(fmaxf(red[0], red[1]), fmaxf(red[2], red[3]));
  f32x4 p;
#pragma unroll
  for (int c = 0; c < 4; ++c) p[c] = exp2f((v[c] - mx) * LOG2E);
  float s = p[0] + p[1] + p[2] + p[3];
#pragma unroll
  for (int off = 1; off < 64; off <<= 1) s += __shfl_xor(s, off);
  if (lane == 0) red[4 + wave] = s;
  __syncthreads();
  s = red[4] + red[5] + red[6] + red[7];
  float inv = 1.0f / s;
  ushort4 o;
  o.x = f2bf(p[0] * inv); o.y = f2bf(p[1] * inv); o.z = f2bf(p[2] * inv); o.w = f2bf(p[3] * inv);
  *(ushort4*)(P + (size_t)row * 1024 + tid * 4) = o;
}

// ---------------------------------------------------------------------------
// Fused attention: per block (b, h, 64-row q-tile).
// Computes S^T tiles (so exp(P)^T in C-layout is directly the B-operand of
// mfma_f32_16x16x16bf16_1k for O^T = Vt * P^T). Writes corr (f32) and attn_out.
// grid 3072 (= 16b * 12h * 16 q-tiles), block 256.
__global__ __launch_bounds__(256) void attn_flash(
    const u16* __restrict__ Qb, const u16* __restrict__ Kb,
    const u16* __restrict__ Qtb, const u16* __restrict__ Vt,
    float* __restrict__ corr_out, float* __restrict__ attn_out) {
  int bid = blockIdx.x;
  int qt = bid & 15;
  int h = (bid >> 4) % 12;
  int b = bid / 192;
  int tid = threadIdx.x, wave = tid >> 6, lane = tid & 63;
  int quad = lane >> 4, l15 = lane & 15;

  __shared__ u16 qts[64 * 64];
  __shared__ u16 qs[64 * 64];
  __shared__ u16 ks[64 * 64];
  __shared__ u16 vts[64 * 64];

  int srow = lane >> 3;      // row within a 1KB staging call (8 rows x 128B)
  int sch = lane & 7;        // physical 16B chunk position
  int scg = sch ^ srow;      // global chunk (XOR swizzle)
  size_t qn0 = (size_t)b * 1024 + qt * 64;

#pragma unroll
  for (int i = 0; i < 2; ++i) {
    int r = (wave * 2 + i) * 8 + srow;
    gl_lds16(Qtb + (qn0 + r) * 768 + h * 64 + scg * 8, qts + (wave * 2 + i) * 512);
    gl_lds16(Qb + (qn0 + r) * 768 + h * 64 + scg * 8, qs + (wave * 2 + i) * 512);
  }
  __syncthreads();

  // B-operand frags for this wave's 16 columns (n = wave*16 + l15), hoisted
  bf16x8 qtB[2], qB[2];
  {
    int nr = wave * 16 + l15;
#pragma unroll
    for (int s = 0; s < 2; ++s) {
      int ph = (s * 4 + quad) ^ (nr & 7);
      qtB[s] = *(const bf16x8*)(qts + nr * 64 + ph * 8);
      qB[s] = *(const bf16x8*)(qs + nr * 64 + ph * 8);
    }
  }

  f32x4 oacc[4] = {};
  float run_m = -1e30f, run_l = 0.0f;
  size_t vrow0 = ((size_t)b * 12 + h) * 64;
  size_t crow = (((size_t)b * 12 + h) * 1024 + qt * 64 + wave * 16 + l15);  // this lane's n-row in corr

  for (int c = 0; c < 16; ++c) {
    __syncthreads();
#pragma unroll
    for (int i = 0; i < 2; ++i) {
      int r = (wave * 2 + i) * 8 + srow;
      gl_lds16(Kb + ((size_t)b * 1024 + c * 64 + r) * 768 + h * 64 + scg * 8, ks + (wave * 2 + i) * 512);
      gl_lds16(Vt + (vrow0 + r) * 1024 + c * 64 + scg * 8, vts + (wave * 2 + i) * 512);
    }
    __syncthreads();

    f32x4 cacc[4] = {}, sacc[4] = {};
#pragma unroll
    for (int mt = 0; mt < 4; ++mt) {
      int ar = mt * 16 + l15;
#pragma unroll
      for (int s = 0; s < 2; ++s) {
        bf16x8 a = *(const bf16x8*)(ks + ar * 64 + (((s * 4 + quad) ^ (ar & 7)) * 8));
        cacc[mt] = __builtin_amdgcn_mfma_f32_16x16x32_bf16(a, qtB[s], cacc[mt], 0, 0, 0);
        sacc[mt] = __builtin_amdgcn_mfma_f32_16x16x32_bf16(a, qB[s], sacc[mt], 0, 0, 0);
      }
    }

    // corr = cacc/8, store directly (lane holds 4 consecutive m at fixed n)
    float e[16];
#pragma unroll
    for (int mt = 0; mt < 4; ++mt) {
      f32x4 cw = cacc[mt] * 0.125f;
      *(f32x4*)(corr_out + crow * 1024 + (size_t)c * 64 + mt * 16 + quad * 4) = cw;
#pragma unroll
      for (int r = 0; r < 4; ++r) e[mt * 4 + r] = (sacc[mt][r] * 0.125f + cw[r]) * LOG2E;
    }

    // online softmax over m (column stats live in-lane + cross-quad shuffles)
    float mx = e[0];
#pragma unroll
    for (int i = 1; i < 16; ++i) mx = fmaxf(mx, e[i]);
    mx = fmaxf(mx, __shfl_xor(mx, 16));
    mx = fmaxf(mx, __shfl_xor(mx, 32));
    float nm = fmaxf(run_m, mx);
    float alpha = exp2f(run_m - nm);
    float p[16], ps = 0.0f;
#pragma unroll
    for (int i = 0; i < 16; ++i) { p[i] = exp2f(e[i] - nm); ps += p[i]; }
    ps += __shfl_xor(ps, 16);
    ps += __shfl_xor(ps, 32);
    run_l = run_l * alpha + ps;
    run_m = nm;
#pragma unroll
    for (int dt = 0; dt < 4; ++dt) oacc[dt] *= alpha;

    // P^T packed: C-layout (m = quad*4+reg) == 16x16x16 B-operand (k = quad*4+j)
    s16x4 pb[4];
#pragma unroll
    for (int mt = 0; mt < 4; ++mt) {
      s16x4 t;
      t[0] = (short)f2bf(p[mt * 4 + 0]);
      t[1] = (short)f2bf(p[mt * 4 + 1]);
      t[2] = (short)f2bf(p[mt * 4 + 2]);
      t[3] = (short)f2bf(p[mt * 4 + 3]);
      pb[mt] = t;
    }

    // O^T += Vt_tile * P^T  (contraction over this chunk's 64 m, k=16 steps)
#pragma unroll
    for (int dt = 0; dt < 4; ++dt) {
      int vr = dt * 16 + l15;
#pragma unroll
      for (int s = 0; s < 4; ++s) {
        int ph = (s * 2 + (quad >> 1)) ^ (vr & 7);
        s16x4 va = *(const s16x4*)(vts + vr * 64 + ph * 8 + (quad & 1) * 4);
        oacc[dt] = __builtin_amdgcn_mfma_f32_16x16x16bf16_1k(va, pb[s], oacc[dt], 0, 0, 0);
      }
    }
  }

  float inv = 1.0f / run_l;
  size_t onr = (size_t)b * 1024 + qt * 64 + wave * 16 + l15;
#pragma unroll
  for (int dt = 0; dt < 4; ++dt) {
    f32x4 v = oacc[dt] * inv;
    *(f32x4*)(attn_out + onr * 768 + h * 64 + dt * 16 + quad * 4) = v;
  }
}

// ---------------------------------------------------------------------------
extern "C" void kernel_launch(void* const* d_in, const int* in_sizes, int n_in,
                              void* d_out, int out_size, void* d_ws, size_t ws_size,
                              hipStream_t stream) {
  (void)in_sizes; (void)n_in; (void)out_size; (void)ws_size;
  const float* features = (const float*)d_in[0];
  const float* locf = (const float*)d_in[1];
  const float* w_q = (const float*)d_in[2];
  const float* b_q = (const float*)d_in[3];
  const float* w_k = (const float*)d_in[4];
  const float* b_k = (const float*)d_in[5];
  const float* w_v = (const float*)d_in[6];
  const float* b_v = (const float*)d_in[7];
  const float* w_qt = (const float*)d_in[8];
  const float* b_qt = (const float*)d_in[9];
  const float* w_kl = (const float*)d_in[10];
  const float* b_kl = (const float*)d_in[11];
  const float* pos = (const float*)d_in[12];
  const float* gamma = (const float*)d_in[13];
  const float* beta = (const float*)d_in[14];

  // ws (needs ~132 MB): Wt[5] | biases[4] | Qb | Kb | Vb | Qtb | Vt
  u16* Wt = (u16*)d_ws;
  float* wsb = (float*)((char*)d_ws + 5898240);
  u16* Qb = (u16*)((char*)d_ws + 5898240 + 12288);
  u16* Kb = Qb + 12582912;
  u16* Vb = Kb + 12582912;
  u16* Qtb = Vb + 12582912;
  u16* Vtr = Qtb + 12582912;

  float* attn_out = (float*)d_out;                 // 12582912 f32
  float* loc_out = attn_out + 12582912;            // 12582912 f32
  float* corr_out = attn_out + 25165824;           // 201326592 f32
  // loc-branch scratch lives inside the corr region (consumed before attn_flash runs)
  u16* Xbf = (u16*)corr_out;
  u16* normed = Xbf + 12582912;
  u16* normt = normed + 12582912;
  float* G = (float*)(normt + 12582912);
  u16* Ploc = (u16*)(G + 16777216);
  u16* loctmp = Ploc + 16777216;

  prep_w<<<dim3(12, 12, 5), 256, 0, stream>>>(w_q, w_k, w_v, w_qt, w_kl, Wt);
  copy_biases<<<3, 256, 0, stream>>>(b_q, b_k, b_v, b_qt, wsb);
  convert_x<<<12288, 256, 0, stream>>>(features, Xbf);
  ln_rows<<<4096, 256, 0, stream>>>(locf, pos, gamma, beta, normed);
  transpose_bf16<<<dim3(16, 12, 16), 256, 0, stream>>>(normed, normt, 0);
  // projections: [16384,768] x W^T for z in {q,k,v,qt} -> Qb,Kb,Vb,Qtb (+bias)
  gemm_bt<<<dim3(6, 128, 4), 256, 0, stream>>>(Xbf, 768, 0L, Wt, 768, 589824L,
                                               (void*)Qb, 768, 12582912L, 1, wsb, 768, 768, 1.0f);
  transpose_bf16<<<dim3(16, 12, 16), 256, 0, stream>>>(Vb, Vtr, 1);
  // G[b] = Qt_full K_full^T / 96  (= mean_h corr)
  gemm_bt<<<dim3(8, 8, 16), 256, 0, stream>>>(Qtb, 768, 786432L, Kb, 768, 786432L,
                                              (void*)G, 1024, 1048576L, 0, nullptr, 0, 768, 1.0f / 96.0f);
  softmax_rows<<<16384, 256, 0, stream>>>(G, Ploc);
  // loc_tmp[b] = P[b] @ normed[b]   (B operand = normed^T, k-major over m)
  gemm_bt<<<dim3(6, 8, 16), 256, 0, stream>>>(Ploc, 1024, 1048576L, normt, 1024, 786432L,
                                              (void*)loctmp, 768, 786432L, 1, nullptr, 0, 1024, 1.0f);
  // loc_out = loc_tmp @ w_k_loc + b_k_loc
  gemm_bt<<<dim3(6, 128, 1), 256, 0, stream>>>(loctmp, 768, 0L, Wt + 4 * 589824, 768, 0L,
                                               (void*)loc_out, 768, 0L, 0, b_kl, 0, 768, 1.0f);
  // fused attention + corr output (overwrites the scratch region)
  attn_flash<<<3072, 256, 0, stream>>>(Qb, Kb, Qtb, Vtr, corr_out, attn_out);
}